// Round 6
// baseline (278.951 us; speedup 1.0000x reference)
//
#include <hip/hip_runtime.h>
#include <hip/hip_fp16.h>

#define NB 512
#define DD 128
#define SS 50
#define TT 32
#define LL 64
#define CLIPN 50
#define NFRIENDS 10000
#define NTHREADS 512
#define NWAVES 8
#define PAD1 50001              // word table rows (PAD+1)
#define WELEMS (PAD1 * DD)      // 6,400,128 (divisible by 16)

typedef unsigned short u16;
typedef unsigned int u32;
typedef _Float16 h2 __attribute__((ext_vector_type(2)));
typedef __fp16 hf2 __attribute__((ext_vector_type(2)));

__device__ __forceinline__ float bf2f(u32 u) {
    union { u32 i; float f; } c; c.i = u << 16; return c.f;
}
__device__ __forceinline__ u16 f2bf(float f) {
    union { float f; u32 i; } c; c.f = f;
    u32 x = c.i;
    return (u16)((x + 0x7fffu + ((x >> 16) & 1u)) >> 16);
}
__device__ __forceinline__ float sigf(float x) { return 1.f / (1.f + __expf(-x)); }

__device__ __forceinline__ h2 u2h(u32 x) { union { u32 u; h2 h; } c; c.u = x; return c.h; }
__device__ __forceinline__ u32 h2u(h2 x) { union { h2 h; u32 u; } c; c.h = x; return c.u; }
__device__ __forceinline__ h2 pkrtz(float a, float b) {
    union { hf2 p; h2 h; } c; c.p = __builtin_amdgcn_cvt_pkrtz(a, b); return c.h;
}
// e5m2 byte -> f16 is a left-shift by 8; v_perm builds a half2 pair in ONE op.
__device__ __forceinline__ h2 declo(u32 w) {
    return u2h(__builtin_amdgcn_perm(w, 0u, 0x05010400u));  // [0,b0,0,b1]
}
__device__ __forceinline__ h2 dechi(u32 w) {
    return u2h(__builtin_amdgcn_perm(w, 0u, 0x07010600u));  // [0,b2,0,b3]
}
#define FD2(a, b, c) __builtin_amdgcn_fdot2((a), (b), (c), false)

// ---- e5m2 encode (for the convert kernel) ---------------------------------
__device__ __forceinline__ u32 e5m2_byte(float x) {
    u16 h = __half_as_ushort(__float2half(x));          // f32 -> f16 RNE
    u16 r = (u16)(h + 0x7Fu + ((h >> 8) & 1u));         // RNE to top byte
    return (r >> 8) & 0xffu;
}
__device__ __forceinline__ u32 e5m2_enc4(const float* v) {
    return e5m2_byte(v[0]) | (e5m2_byte(v[1]) << 8) |
           (e5m2_byte(v[2]) << 16) | (e5m2_byte(v[3]) << 24);
}

// ---- dtype-generic scalar load/store --------------------------------------
template <bool BF16> struct LD;
template <> struct LD<true> {
    static __device__ __forceinline__ float one(const void* p, long i) {
        return bf2f(((const u16*)p)[i]);
    }
    static __device__ __forceinline__ void st(void* p, long i, float v) {
        ((u16*)p)[i] = f2bf(v);
    }
    // vectorized 64-elem row dot vs f32 vector q (row must be 16B-aligned)
    static __device__ __forceinline__ float dot64(const void* p, long base,
                                                  const float* q) {
        const uint4* r = (const uint4*)((const u16*)p + base);
        float acc = 0.f;
        #pragma unroll
        for (int j = 0; j < 8; ++j) {
            uint4 v = r[j];
            const float* qq = q + 8 * j;
            acc += bf2f(v.x & 0xffffu) * qq[0] + bf2f(v.x >> 16) * qq[1]
                 + bf2f(v.y & 0xffffu) * qq[2] + bf2f(v.y >> 16) * qq[3]
                 + bf2f(v.z & 0xffffu) * qq[4] + bf2f(v.z >> 16) * qq[5]
                 + bf2f(v.w & 0xffffu) * qq[6] + bf2f(v.w >> 16) * qq[7];
        }
        return acc;
    }
};
template <> struct LD<false> {
    static __device__ __forceinline__ float one(const void* p, long i) {
        return ((const float*)p)[i];
    }
    static __device__ __forceinline__ void st(void* p, long i, float v) {
        ((float*)p)[i] = v;
    }
    static __device__ __forceinline__ float dot64(const void* p, long base,
                                                  const float* q) {
        const float4* r = (const float4*)((const float*)p + base);
        float acc = 0.f;
        #pragma unroll
        for (int j = 0; j < 16; ++j) {
            float4 v = r[j];
            const float* qq = q + 4 * j;
            acc += v.x * qq[0] + v.y * qq[1] + v.z * qq[2] + v.w * qq[3];
        }
        return acc;
    }
};

// ---- word-table accessors for the fallback path: WM 0=fp32, 1=bf16 --------
template <int WM> struct WT;
template <> struct WT<0> {
    static __device__ __forceinline__ void sixteen(const void* p, long i, float* o) {
        const float* s = (const float*)p + i;
        #pragma unroll
        for (int j = 0; j < 4; ++j) {
            float4 v = *(const float4*)(s + 4 * j);
            o[4*j] = v.x; o[4*j+1] = v.y; o[4*j+2] = v.z; o[4*j+3] = v.w;
        }
    }
    static __device__ __forceinline__ void four(const void* p, long i, float* o) {
        float4 v = *(const float4*)((const float*)p + i);
        o[0] = v.x; o[1] = v.y; o[2] = v.z; o[3] = v.w;
    }
};
template <> struct WT<1> {
    static __device__ __forceinline__ void sixteen(const void* p, long i, float* o) {
        const u16* s = (const u16*)p + i;
        #pragma unroll
        for (int j = 0; j < 2; ++j) {
            uint4 v = *(const uint4*)(s + 8 * j);
            float* q = o + 8 * j;
            q[0] = bf2f(v.x & 0xffffu); q[1] = bf2f(v.x >> 16);
            q[2] = bf2f(v.y & 0xffffu); q[3] = bf2f(v.y >> 16);
            q[4] = bf2f(v.z & 0xffffu); q[5] = bf2f(v.z >> 16);
            q[6] = bf2f(v.w & 0xffffu); q[7] = bf2f(v.w >> 16);
        }
    }
    static __device__ __forceinline__ void four(const void* p, long i, float* o) {
        uint2 v = *(const uint2*)((const u16*)p + i);
        o[0] = bf2f(v.x & 0xffffu); o[1] = bf2f(v.x >> 16);
        o[2] = bf2f(v.y & 0xffffu); o[3] = bf2f(v.y >> 16);
    }
};

// ---- in-kernel dtype sniff (fallback path only) ---------------------------
__device__ __forceinline__ int sniff_wave(const u16* p, int lane) {
    int bad = 0;
    #pragma unroll
    for (int j = 0; j < 8; ++j) {
        unsigned e = (p[lane * 8 + j] >> 7) & 0xffu;
        bad += (e >= 127u);
    }
    #pragma unroll
    for (int off = 1; off < 64; off <<= 1) bad += __shfl_xor(bad, off, 64);
    return (bad <= 16) ? 1 : 0;   // 1 = bf16, 0 = fp32
}

// ---- word table -> e5m2 in workspace; publishes dtype flag ---------------
__global__ void convert_words(const void* __restrict__ src, u32* __restrict__ dst,
                              u32* __restrict__ flagp) {
    __shared__ int s_flag;
    if (threadIdx.x < 64) {
        int f = sniff_wave((const u16*)src, (int)threadIdx.x);
        if (threadIdx.x == 0) s_flag = f;
    }
    __syncthreads();
    if (blockIdx.x == 0 && threadIdx.x == 0) flagp[0] = (u32)s_flag;
    long idx = (long)blockIdx.x * 256 + threadIdx.x;
    long i = idx * 16;
    if (i >= WELEMS) return;
    float v[16];
    if (s_flag == 0) {                        // fp32 source
        const float* s = (const float*)src + i;
        #pragma unroll
        for (int j = 0; j < 4; ++j) {
            float4 q = *(const float4*)(s + 4 * j);
            v[4*j] = q.x; v[4*j+1] = q.y; v[4*j+2] = q.z; v[4*j+3] = q.w;
        }
    } else {                                  // bf16 source
        WT<1>::sixteen(src, i, v);
    }
    uint4 o;
    o.x = e5m2_enc4(v); o.y = e5m2_enc4(v + 4);
    o.z = e5m2_enc4(v + 8); o.w = e5m2_enc4(v + 12);
    *(uint4*)(dst + idx * 4) = o;
}

// ---- shared-memory layout (single allocation for both dtype bodies) -------
struct SM {
    alignas(16) float sent[SS * DD];
    alignas(16) int   uti[SS * TT];        // 16B-aligned for uint4 reads
    alignas(16) float ww[NWAVES][TT];      // per-wave unnormalized weights
    float mem[DD];
    float item[LL];
    float sw[SS];
    float swf[SS];
    float swp[SS * 32];
    float q[LL];
    float ept[LL];
    float uemb[LL];
    int   fidx[CLIPN];
    float g[CLIPN];
    float a1[32];
    float a2[16];
    float alpha[2];
    float fnum;
    int   flag;
};

// ===========================================================================
// Fast body: e5m2 table, perm-decode -> half2, fdot2 score.
// R6: weighted pass gathers columns DIRECTLY from global (L2-resident table)
// instead of LDS tile transpose -- deletes the stash + tile reads (the
// standing 4-way bank conflict). Gathers issued at iteration top so the
// score pass + softmax hide their L2 latency.
// ===========================================================================
template <bool BF16>
__device__ __forceinline__ void nrs_body(SM& sm,
              const int* __restrict__ user_idx,
              const int* __restrict__ item_idx,
              const void* __restrict__ wtab,
              const void* __restrict__ emb_item,
              const void* __restrict__ emb_user,
              const void* __restrict__ W_mem, const void* __restrict__ b_mem,
              const void* __restrict__ w_word, const void* __restrict__ b_word,
              const void* __restrict__ w_sent, const void* __restrict__ b_sent,
              const void* __restrict__ W_tr, const void* __restrict__ b_tr,
              const void* __restrict__ W1, const void* __restrict__ b1,
              const void* __restrict__ W2, const void* __restrict__ b2,
              const void* __restrict__ W3, const void* __restrict__ b3,
              const void* __restrict__ w_aff, const void* __restrict__ b_aff,
              const int* __restrict__ uti, const int* __restrict__ ufi,
              void* __restrict__ out)
{
    const int b = blockIdx.x;
    const int tid = (int)threadIdx.x;
    const int lane = tid & 63;
    const int wave = tid >> 6;

    const int u = user_idx[b];
    const int it = item_idx[b];
    const long utb = (long)u * (SS * TT);

    if (tid < LL) sm.item[tid] = LD<BF16>::one(emb_item, (long)it * LL + tid);
    __syncthreads();

    // mem = item_emb @ W_mem + b_mem (tid<128) | stage tweet indices (all)
    for (int i = tid; i < SS * TT; i += NTHREADS) sm.uti[i] = uti[utb + i];
    if (tid < DD) {
        float acc = LD<BF16>::one(b_mem, tid);
        #pragma unroll 8
        for (int l = 0; l < LL; ++l)
            acc += sm.item[l] * LD<BF16>::one(W_mem, l * DD + tid);
        sm.mem[tid] = acc;
    }
    __syncthreads();

    const float bw = LD<BF16>::one(b_word, 0);
    const float bs = LD<BF16>::one(b_sent, 0);
    const int t = lane >> 1, h = lane & 1;   // score-pass mapping: lane = 2t+h
    const int dq = lane & 31, th = lane >> 5;// weighted-pass mapping
    float ww4[4];
    #pragma unroll
    for (int k = 0; k < 4; ++k) ww4[k] = LD<BF16>::one(w_word, 4 * dq + k);
    const float ws0 = LD<BF16>::one(w_sent, lane);
    const float ws1 = LD<BF16>::one(w_sent, lane + 64);

    h2 memh[32];

    for (int hoop = 0; hoop < 2; ++hoop) {
        // mem (f32, LDS) -> half2 pairs in registers for this lane's half
        {
            const float* mrow = &sm.mem[h * 64];
            #pragma unroll
            for (int k = 0; k < 32; ++k)
                memh[k] = pkrtz(mrow[2 * k], mrow[2 * k + 1]);
        }

        // prefetch first sentence's score-pass rows into registers
        uint4 w[4];
        {
            const int row0 = sm.uti[wave * TT + t];
            const uint4* gp0 = (const uint4*)((const char*)wtab +
                                              ((row0 << 7) + (h << 6)));
            #pragma unroll
            for (int j = 0; j < 4; ++j) w[j] = gp0[j];
        }

        for (int s = wave; s < SS; s += NWAVES) {
            // ---- issue next sentence's score gathers (consumed next iter) ----
            uint4 wn[4];
            {
                const int sn = (s + NWAVES < SS) ? (s + NWAVES) : s;
                const int rown = sm.uti[sn * TT + t];
                const uint4* gpn = (const uint4*)((const char*)wtab +
                                                  ((rown << 7) + (h << 6)));
                #pragma unroll
                for (int j = 0; j < 4; ++j) wn[j] = gpn[j];
            }

            // ---- issue this sentence's WEIGHTED-pass column gathers now:
            // lane (th,dq) needs word dq of rows t2 = th*16..th*16+15.
            // L2-resident; latency hidden under score + softmax below.
            uint4 idx4[4];
            #pragma unroll
            for (int j = 0; j < 4; ++j)
                idx4[j] = *(const uint4*)&sm.uti[s * TT + th * 16 + 4 * j];
            u32 wrd[16];
            #pragma unroll
            for (int j = 0; j < 4; ++j) {
                wrd[4*j+0] = *(const u32*)((const char*)wtab +
                              (((long)(int)idx4[j].x << 7) + (dq << 2)));
                wrd[4*j+1] = *(const u32*)((const char*)wtab +
                              (((long)(int)idx4[j].y << 7) + (dq << 2)));
                wrd[4*j+2] = *(const u32*)((const char*)wtab +
                              (((long)(int)idx4[j].z << 7) + (dq << 2)));
                wrd[4*j+3] = *(const u32*)((const char*)wtab +
                              (((long)(int)idx4[j].w << 7) + (dq << 2)));
            }

            // ---- score: lane = 2t+h owns 64 dims of row t; 4 parallel chains
            float a0 = 0.f, a1 = 0.f, a2 = 0.f, a3 = 0.f;
            #pragma unroll
            for (int j = 0; j < 4; ++j) {
                float* ap = (j == 0) ? &a0 : (j == 1) ? &a1 : (j == 2) ? &a2 : &a3;
                float ac = *ap;
                ac = FD2(declo(w[j].x), memh[8*j + 0], ac);
                ac = FD2(dechi(w[j].x), memh[8*j + 1], ac);
                ac = FD2(declo(w[j].y), memh[8*j + 2], ac);
                ac = FD2(dechi(w[j].y), memh[8*j + 3], ac);
                ac = FD2(declo(w[j].z), memh[8*j + 4], ac);
                ac = FD2(dechi(w[j].z), memh[8*j + 5], ac);
                ac = FD2(declo(w[j].w), memh[8*j + 6], ac);
                ac = FD2(dechi(w[j].w), memh[8*j + 7], ac);
                *ap = ac;
            }
            float acc = (a0 + a1) + (a2 + a3);
            acc += __shfl_xor(acc, 1, 64);   // score[t] in lanes 2t, 2t+1

            // unnormalized weight (|score| << 1 -> exp safe); publish to wave
            const float e = __expf(acc);
            if (h == 0) sm.ww[wave][t] = e;

            // broadcast-read this half's 16 unnormalized weights, pack to h2
            h2 wh2[16];
            {
                const float* wp = &sm.ww[wave][th * 16];
                #pragma unroll
                for (int jj = 0; jj < 4; ++jj) {
                    float4 qv = *(const float4*)(wp + 4 * jj);
                    wh2[4*jj+0] = pkrtz(qv.x, qv.x);
                    wh2[4*jj+1] = pkrtz(qv.y, qv.y);
                    wh2[4*jj+2] = pkrtz(qv.z, qv.z);
                    wh2[4*jj+3] = pkrtz(qv.w, qv.w);
                }
            }

            // ---- weighted pass (e-weighted) on the prefetched columns ----
            h2 p0a = u2h(0u), p0b = u2h(0u), p1a = u2h(0u), p1b = u2h(0u);
            #pragma unroll
            for (int i2 = 0; i2 < 16; ++i2) {
                const u32 wv = wrd[i2];
                const h2 wh = wh2[i2];
                if (i2 & 1) { p0b += declo(wv) * wh; p1b += dechi(wv) * wh; }
                else        { p0a += declo(wv) * wh; p1a += dechi(wv) * wh; }
            }
            h2 pa0 = p0a + p0b, pa1 = p1a + p1b;
            pa0 += u2h((u32)__shfl_xor((int)h2u(pa0), 32, 64));
            pa1 += u2h((u32)__shfl_xor((int)h2u(pa1), 32, 64));

            // softmax denominator (no consumer until here -> overlaps above)
            float smd = e;
            #pragma unroll
            for (int off = 2; off < 64; off <<= 1) smd += __shfl_xor(smd, off, 64);
            const float inv = 1.f / smd;

            const float f0 = (float)pa0.x * inv, f1 = (float)pa0.y * inv;
            const float f2 = (float)pa1.x * inv, f3 = (float)pa1.y * inv;
            if (th == 0) {
                *(float4*)&sm.sent[s * DD + 4 * dq] = make_float4(f0, f1, f2, f3);
                // sw partial (4 dims); reduced in the batched phase below
                sm.swp[s * 32 + dq] =
                    f0 * ww4[0] + f1 * ww4[1] + f2 * ww4[2] + f3 * ww4[3];
            }

            // rotate prefetch buffer
            #pragma unroll
            for (int j = 0; j < 4; ++j) w[j] = wn[j];
        }
        __syncthreads();

        // batched sw reduction: each wave reduces its own sentences (ILP-rich)
        for (int s2 = wave; s2 < SS; s2 += NWAVES) {
            float v = sm.swp[s2 * 32 + (lane & 31)];
            #pragma unroll
            for (int off = 1; off < 32; off <<= 1) v += __shfl_xor(v, off, 64);
            if (lane == 0) sm.sw[s2] = v + bw;
        }
        __syncthreads();

        // sentence-level softmax (wave 0); tanh in [-1,1] -> no max needed
        if (wave == 0) {
            float p = sm.mem[lane] * ws0 + sm.mem[lane + 64] * ws1;
            #pragma unroll
            for (int off = 1; off < 64; off <<= 1) p += __shfl_xor(p, off, 64);
            float iw = p + bs;
            float e2 = (lane < SS) ? __expf(tanhf(sm.sw[lane] + iw)) : 0.f;
            float smm = e2;
            #pragma unroll
            for (int off = 1; off < 64; off <<= 1) smm += __shfl_xor(smm, off, 64);
            if (lane < SS) sm.swf[lane] = e2 / smm;
        }
        __syncthreads();

        if (tid < DD) {
            float acc = sm.mem[tid];
            for (int s2 = 0; s2 < SS; ++s2)
                acc += sm.swf[s2] * sm.sent[s2 * DD + tid];
            sm.mem[tid] = acc;
        }
        __syncthreads();
    }

    // ---------------- tail ----------------
    if (tid < LL) {
        float acc = LD<BF16>::one(b_tr, tid);
        for (int d = 0; d < DD; ++d)
            acc += sm.mem[d] * LD<BF16>::one(W_tr, d * LL + tid);
        sm.ept[tid] = acc;
    } else if (tid < 128) {
        int l = tid - 64;
        sm.q[l] = sm.item[l] * LD<BF16>::one(w_aff, l);
    } else if (tid < 128 + CLIPN) {
        sm.fidx[tid - 128] = ufi[(long)u * CLIPN + (tid - 128)];
    } else if (tid >= 192 && tid < 224) {
        int j = tid - 192;
        float acc = LD<BF16>::one(b1, j);
        for (int l = 0; l < LL; ++l)
            acc += sm.item[l] * LD<BF16>::one(W1, l * 32 + j);
        sm.a1[j] = sigf(acc);
    }
    __syncthreads();

    const float baff = LD<BF16>::one(b_aff, 0);
    if (tid < CLIPN) {
        long fb = (long)sm.fidx[tid] * LL;
        float g = sigf(LD<BF16>::dot64(emb_user, fb, sm.q) + baff);
        sm.g[tid] = g;
        LD<BF16>::st(out, NB + (long)b * CLIPN + tid, g);
    } else if (tid >= 64 && tid < 80) {
        int j = tid - 64;
        float acc = LD<BF16>::one(b2, j);
        for (int k = 0; k < 32; ++k) acc += sm.a1[k] * LD<BF16>::one(W2, k * 16 + j);
        sm.a2[j] = sigf(acc);
    } else if (tid == 80) {
        int cnt = 0;
        for (int c = 0; c < CLIPN; ++c) cnt += (sm.fidx[c] == NFRIENDS);
        sm.fnum = (float)(CLIPN - cnt);
    }
    __syncthreads();

    if (tid >= 64 && tid < 128) {
        int l = tid - 64;
        float acc = 0.f;
        for (int c = 0; c < CLIPN; ++c)
            acc += sm.g[c] * LD<BF16>::one(emb_user, (long)sm.fidx[c] * LL + l);
        sm.uemb[l] = acc;
    } else if (tid < 2) {
        float acc = LD<BF16>::one(b3, tid);
        for (int k = 0; k < 16; ++k) acc += sm.a2[k] * LD<BF16>::one(W3, k * 2 + tid);
        sm.alpha[tid] = sigf(acc);
    }
    __syncthreads();

    if (wave == 0) {
        float vec = sm.alpha[0] * sm.ept[lane] + sm.alpha[1] * (sm.uemb[lane] / sm.fnum);
        float p = vec * sm.q[lane];
        #pragma unroll
        for (int off = 1; off < 64; off <<= 1) p += __shfl_xor(p, off, 64);
        if (lane == 0) LD<BF16>::st(out, b, sigf(p + baff));
    }
}

// single kernel: uniform branch on dtype flag; one shared allocation
__global__ __launch_bounds__(NTHREADS, 4)
void nrs_fast(const int* __restrict__ user_idx,
              const int* __restrict__ item_idx,
              const void* __restrict__ wtab,
              const void* __restrict__ emb_item,
              const void* __restrict__ emb_user,
              const void* __restrict__ W_mem, const void* __restrict__ b_mem,
              const void* __restrict__ w_word, const void* __restrict__ b_word,
              const void* __restrict__ w_sent, const void* __restrict__ b_sent,
              const void* __restrict__ W_tr, const void* __restrict__ b_tr,
              const void* __restrict__ W1, const void* __restrict__ b1,
              const void* __restrict__ W2, const void* __restrict__ b2,
              const void* __restrict__ W3, const void* __restrict__ b3,
              const void* __restrict__ w_aff, const void* __restrict__ b_aff,
              const int* __restrict__ uti, const int* __restrict__ ufi,
              void* __restrict__ out,
              const u32* __restrict__ flagp)
{
    __shared__ SM sm;
    if (threadIdx.x == 0) sm.flag = (int)flagp[0];
    __syncthreads();
    if (sm.flag == 1)
        nrs_body<true>(sm, user_idx, item_idx, wtab, emb_item, emb_user,
                       W_mem, b_mem, w_word, b_word, w_sent, b_sent, W_tr, b_tr,
                       W1, b1, W2, b2, W3, b3, w_aff, b_aff, uti, ufi, out);
    else
        nrs_body<false>(sm, user_idx, item_idx, wtab, emb_item, emb_user,
                        W_mem, b_mem, w_word, b_word, w_sent, b_sent, W_tr, b_tr,
                        W1, b1, W2, b2, W3, b3, w_aff, b_aff, uti, ufi, out);
}

// ===========================================================================
// Fallback generic kernel (no workspace): original structure, WM 0/1 only.
// ===========================================================================
template <bool BF16, int WM>
__global__ __launch_bounds__(NTHREADS, 4)
void nrs_generic(const int* __restrict__ user_idx,
                 const int* __restrict__ item_idx,
                 const void* __restrict__ wtab,
                 const void* __restrict__ emb_item,
                 const void* __restrict__ emb_user,
                 const void* __restrict__ W_mem, const void* __restrict__ b_mem,
                 const void* __restrict__ w_word, const void* __restrict__ b_word,
                 const void* __restrict__ w_sent, const void* __restrict__ b_sent,
                 const void* __restrict__ W_tr, const void* __restrict__ b_tr,
                 const void* __restrict__ W1, const void* __restrict__ b1,
                 const void* __restrict__ W2, const void* __restrict__ b2,
                 const void* __restrict__ W3, const void* __restrict__ b3,
                 const void* __restrict__ w_aff, const void* __restrict__ b_aff,
                 const int* __restrict__ uti, const int* __restrict__ ufi,
                 void* __restrict__ out)
{
    __shared__ float s_mem[DD];
    __shared__ float s_item[LL];
    __shared__ float s_sent[SS * DD];
    __shared__ int   s_uti[SS * TT];
    __shared__ float s_sw[SS];
    __shared__ float s_swf[SS];
    __shared__ float s_q[LL];
    __shared__ float s_ept[LL];
    __shared__ float s_uemb[LL];
    __shared__ int   s_fidx[CLIPN];
    __shared__ float s_g[CLIPN];
    __shared__ float s_a1[32];
    __shared__ float s_a2[16];
    __shared__ float s_alpha[2];
    __shared__ float s_fnum;
    __shared__ int   s_flag;

    const int b = blockIdx.x;
    const int tid = (int)threadIdx.x;
    const int lane = tid & 63;
    const int wave = tid >> 6;

    if (tid < 64) {
        int f = sniff_wave((const u16*)wtab, lane);
        if (tid == 0) s_flag = f;
    }
    __syncthreads();
    if (s_flag != (BF16 ? 1 : 0)) return;

    const int u = user_idx[b];
    const int it = item_idx[b];
    const long utb = (long)u * (SS * TT);

    if (tid < LL) s_item[tid] = LD<BF16>::one(emb_item, (long)it * LL + tid);
    __syncthreads();

    for (int i = tid; i < SS * TT; i += NTHREADS) s_uti[i] = uti[utb + i];
    if (tid < DD) {
        float acc = LD<BF16>::one(b_mem, tid);
        #pragma unroll 8
        for (int l = 0; l < LL; ++l)
            acc += s_item[l] * LD<BF16>::one(W_mem, l * DD + tid);
        s_mem[tid] = acc;
    }
    __syncthreads();

    const float bw = LD<BF16>::one(b_word, 0);
    const float bs = LD<BF16>::one(b_sent, 0);
    const int dq = lane & 31;
    const int th = lane >> 5;
    float ww4[4];
    #pragma unroll
    for (int k = 0; k < 4; ++k) ww4[k] = LD<BF16>::one(w_word, 4 * dq + k);
    const float ws0 = LD<BF16>::one(w_sent, lane);
    const float ws1 = LD<BF16>::one(w_sent, lane + 64);

    for (int hoop = 0; hoop < 2; ++hoop) {
        for (int s = wave; s < SS; s += NWAVES) {
            const int t = lane >> 1, h = lane & 1;
            const int row = s_uti[s * TT + t];
            const long base = (long)row * DD + h * 64;
            float acc = 0.f;
            #pragma unroll
            for (int j = 0; j < 4; ++j) {
                float v16[16];
                WT<WM>::sixteen(wtab, base + 16 * j, v16);
                const float* mp = &s_mem[h * 64 + 16 * j];
                #pragma unroll
                for (int k = 0; k < 16; ++k) acc += v16[k] * mp[k];
            }
            acc += __shfl_xor(acc, 1, 64);

            float mx = acc;
            #pragma unroll
            for (int off = 1; off < 64; off <<= 1) mx = fmaxf(mx, __shfl_xor(mx, off, 64));
            float e = expf(acc - mx);
            float sm = e;
            #pragma unroll
            for (int off = 1; off < 64; off <<= 1) sm += __shfl_xor(sm, off, 64);
            float wwt = 2.f * e / sm;

            float a4[4] = {0.f, 0.f, 0.f, 0.f};
            #pragma unroll 4
            for (int i2 = 0; i2 < 16; ++i2) {
                int t2 = th * 16 + i2;
                float wv = __shfl(wwt, 2 * t2, 64);
                int r2 = s_uti[s * TT + t2];
                float v4[4];
                WT<WM>::four(wtab, (long)r2 * DD + 4 * dq, v4);
                #pragma unroll
                for (int k = 0; k < 4; ++k) a4[k] += wv * v4[k];
            }
            #pragma unroll
            for (int k = 0; k < 4; ++k) a4[k] += __shfl_xor(a4[k], 32, 64);
            if (th == 0)
                *(float4*)&s_sent[s * DD + 4 * dq] =
                    make_float4(a4[0], a4[1], a4[2], a4[3]);

            float p = a4[0] * ww4[0] + a4[1] * ww4[1] + a4[2] * ww4[2] + a4[3] * ww4[3];
            #pragma unroll
            for (int off = 1; off < 64; off <<= 1) p += __shfl_xor(p, off, 64);
            if (lane == 0) s_sw[s] = 0.5f * p + bw;
        }
        __syncthreads();

        if (wave == 0) {
            float p = s_mem[lane] * ws0 + s_mem[lane + 64] * ws1;
            #pragma unroll
            for (int off = 1; off < 64; off <<= 1) p += __shfl_xor(p, off, 64);
            float iw = p + bs;
            float v = (lane < SS) ? tanhf(s_sw[lane] + iw) : -2.f;
            float mx = v;
            #pragma unroll
            for (int off = 1; off < 64; off <<= 1) mx = fmaxf(mx, __shfl_xor(mx, off, 64));
            float e = (lane < SS) ? expf(v - mx) : 0.f;
            float sm = e;
            #pragma unroll
            for (int off = 1; off < 64; off <<= 1) sm += __shfl_xor(sm, off, 64);
            if (lane < SS) s_swf[lane] = e / sm;
        }
        __syncthreads();

        if (tid < DD) {
            float acc = s_mem[tid];
            for (int s2 = 0; s2 < SS; ++s2)
                acc += s_swf[s2] * s_sent[s2 * DD + tid];
            s_mem[tid] = acc;
        }
        __syncthreads();
    }

    if (tid < LL) {
        float acc = LD<BF16>::one(b_tr, tid);
        for (int d = 0; d < DD; ++d)
            acc += s_mem[d] * LD<BF16>::one(W_tr, d * LL + tid);
        s_ept[tid] = acc;
    } else if (tid < 128) {
        int l = tid - 64;
        s_q[l] = s_item[l] * LD<BF16>::one(w_aff, l);
    } else if (tid < 128 + CLIPN) {
        s_fidx[tid - 128] = ufi[(long)u * CLIPN + (tid - 128)];
    } else if (tid >= 192 && tid < 224) {
        int j = tid - 192;
        float acc = LD<BF16>::one(b1, j);
        for (int l = 0; l < LL; ++l)
            acc += s_item[l] * LD<BF16>::one(W1, l * 32 + j);
        s_a1[j] = sigf(acc);
    }
    __syncthreads();

    const float baff = LD<BF16>::one(b_aff, 0);
    if (tid < CLIPN) {
        long fb = (long)s_fidx[tid] * LL;
        float acc = 0.f;
        for (int l = 0; l < LL; ++l) acc += LD<BF16>::one(emb_user, fb + l) * s_q[l];
        float g = sigf(acc + baff);
        s_g[tid] = g;
        LD<BF16>::st(out, NB + (long)b * CLIPN + tid, g);
    } else if (tid >= 64 && tid < 80) {
        int j = tid - 64;
        float acc = LD<BF16>::one(b2, j);
        for (int k = 0; k < 32; ++k) acc += s_a1[k] * LD<BF16>::one(W2, k * 16 + j);
        s_a2[j] = sigf(acc);
    } else if (tid == 80) {
        int cnt = 0;
        for (int c = 0; c < CLIPN; ++c) cnt += (s_fidx[c] == NFRIENDS);
        s_fnum = (float)(CLIPN - cnt);
    }
    __syncthreads();

    if (tid >= 64 && tid < 128) {
        int l = tid - 64;
        float acc = 0.f;
        for (int c = 0; c < CLIPN; ++c)
            acc += s_g[c] * LD<BF16>::one(emb_user, (long)s_fidx[c] * LL + l);
        s_uemb[l] = acc;
    } else if (tid < 2) {
        float acc = LD<BF16>::one(b3, tid);
        for (int k = 0; k < 16; ++k) acc += s_a2[k] * LD<BF16>::one(W3, k * 2 + tid);
        s_alpha[tid] = sigf(acc);
    }
    __syncthreads();

    if (wave == 0) {
        float vec = s_alpha[0] * s_ept[lane] + s_alpha[1] * (s_uemb[lane] / s_fnum);
        float p = vec * s_q[lane];
        #pragma unroll
        for (int off = 1; off < 64; off <<= 1) p += __shfl_xor(p, off, 64);
        if (lane == 0) LD<BF16>::st(out, b, sigf(p + baff));
    }
}

extern "C" void kernel_launch(void* const* d_in, const int* in_sizes, int n_in,
                              void* d_out, int out_size, void* d_ws, size_t ws_size,
                              hipStream_t stream) {
    (void)in_sizes; (void)n_in; (void)out_size;
    u32* wbuf = (u32*)d_ws;
    u32* flagp = wbuf + (WELEMS / 4);               // flag just past the table
    const bool ws_ok = ws_size >= (size_t)WELEMS + 64;

    if (ws_ok) {
        const long nthr = (WELEMS + 15) / 16;
        convert_words<<<(int)((nthr + 255) / 256), 256, 0, stream>>>(
            d_in[2], wbuf, flagp);
        nrs_fast<<<NB, NTHREADS, 0, stream>>>(
            (const int*)d_in[0], (const int*)d_in[1], (const void*)wbuf,
            d_in[3], d_in[4], d_in[5], d_in[6], d_in[7], d_in[8], d_in[9],
            d_in[10], d_in[11], d_in[12], d_in[13], d_in[14], d_in[15],
            d_in[16], d_in[17], d_in[18], d_in[19], d_in[20],
            (const int*)d_in[21], (const int*)d_in[22], d_out, flagp);
    } else {
        nrs_generic<true, 1><<<NB, NTHREADS, 0, stream>>>(
            (const int*)d_in[0], (const int*)d_in[1], d_in[2],
            d_in[3], d_in[4], d_in[5], d_in[6], d_in[7], d_in[8], d_in[9],
            d_in[10], d_in[11], d_in[12], d_in[13], d_in[14], d_in[15],
            d_in[16], d_in[17], d_in[18], d_in[19], d_in[20],
            (const int*)d_in[21], (const int*)d_in[22], d_out);
        nrs_generic<false, 0><<<NB, NTHREADS, 0, stream>>>(
            (const int*)d_in[0], (const int*)d_in[1], d_in[2],
            d_in[3], d_in[4], d_in[5], d_in[6], d_in[7], d_in[8], d_in[9],
            d_in[10], d_in[11], d_in[12], d_in[13], d_in[14], d_in[15],
            d_in[16], d_in[17], d_in[18], d_in[19], d_in[20],
            (const int*)d_in[21], (const int*)d_in[22], d_out);
    }
}

// Round 7
// 270.783 us; speedup vs baseline: 1.0302x; 1.0302x over previous
//
#include <hip/hip_runtime.h>
#include <hip/hip_fp16.h>

#define NB 512
#define DD 128
#define SS 50
#define TT 32
#define LL 64
#define CLIPN 50
#define NFRIENDS 10000
#define NTHREADS 512
#define NWAVES 8
#define PAD1 50001              // word table rows (PAD+1)
#define WELEMS (PAD1 * DD)      // 6,400,128 (divisible by 16)

typedef unsigned short u16;
typedef unsigned int u32;
typedef _Float16 h2 __attribute__((ext_vector_type(2)));
typedef __fp16 hf2 __attribute__((ext_vector_type(2)));

__device__ __forceinline__ float bf2f(u32 u) {
    union { u32 i; float f; } c; c.i = u << 16; return c.f;
}
__device__ __forceinline__ u16 f2bf(float f) {
    union { float f; u32 i; } c; c.f = f;
    u32 x = c.i;
    return (u16)((x + 0x7fffu + ((x >> 16) & 1u)) >> 16);
}
__device__ __forceinline__ float sigf(float x) { return 1.f / (1.f + __expf(-x)); }

__device__ __forceinline__ h2 u2h(u32 x) { union { u32 u; h2 h; } c; c.u = x; return c.h; }
__device__ __forceinline__ u32 h2u(h2 x) { union { h2 h; u32 u; } c; c.h = x; return c.u; }
__device__ __forceinline__ h2 pkrtz(float a, float b) {
    union { hf2 p; h2 h; } c; c.p = __builtin_amdgcn_cvt_pkrtz(a, b); return c.h;
}
// e5m2 byte -> f16 is a left-shift by 8; v_perm builds a half2 pair in ONE op.
__device__ __forceinline__ h2 declo(u32 w) {
    return u2h(__builtin_amdgcn_perm(w, 0u, 0x05010400u));  // [0,b0,0,b1]
}
__device__ __forceinline__ h2 dechi(u32 w) {
    return u2h(__builtin_amdgcn_perm(w, 0u, 0x07010600u));  // [0,b2,0,b3]
}
#define FD2(a, b, c) __builtin_amdgcn_fdot2((a), (b), (c), false)

// ---- e5m2 encode (for the convert kernel) ---------------------------------
__device__ __forceinline__ u32 e5m2_byte(float x) {
    u16 h = __half_as_ushort(__float2half(x));          // f32 -> f16 RNE
    u16 r = (u16)(h + 0x7Fu + ((h >> 8) & 1u));         // RNE to top byte
    return (r >> 8) & 0xffu;
}
__device__ __forceinline__ u32 e5m2_enc4(const float* v) {
    return e5m2_byte(v[0]) | (e5m2_byte(v[1]) << 8) |
           (e5m2_byte(v[2]) << 16) | (e5m2_byte(v[3]) << 24);
}

// ---- dtype-generic scalar load/store --------------------------------------
template <bool BF16> struct LD;
template <> struct LD<true> {
    static __device__ __forceinline__ float one(const void* p, long i) {
        return bf2f(((const u16*)p)[i]);
    }
    static __device__ __forceinline__ void st(void* p, long i, float v) {
        ((u16*)p)[i] = f2bf(v);
    }
    // vectorized 64-elem row dot vs f32 vector q (row must be 16B-aligned)
    static __device__ __forceinline__ float dot64(const void* p, long base,
                                                  const float* q) {
        const uint4* r = (const uint4*)((const u16*)p + base);
        float acc = 0.f;
        #pragma unroll
        for (int j = 0; j < 8; ++j) {
            uint4 v = r[j];
            const float* qq = q + 8 * j;
            acc += bf2f(v.x & 0xffffu) * qq[0] + bf2f(v.x >> 16) * qq[1]
                 + bf2f(v.y & 0xffffu) * qq[2] + bf2f(v.y >> 16) * qq[3]
                 + bf2f(v.z & 0xffffu) * qq[4] + bf2f(v.z >> 16) * qq[5]
                 + bf2f(v.w & 0xffffu) * qq[6] + bf2f(v.w >> 16) * qq[7];
        }
        return acc;
    }
};
template <> struct LD<false> {
    static __device__ __forceinline__ float one(const void* p, long i) {
        return ((const float*)p)[i];
    }
    static __device__ __forceinline__ void st(void* p, long i, float v) {
        ((float*)p)[i] = v;
    }
    static __device__ __forceinline__ float dot64(const void* p, long base,
                                                  const float* q) {
        const float4* r = (const float4*)((const float*)p + base);
        float acc = 0.f;
        #pragma unroll
        for (int j = 0; j < 16; ++j) {
            float4 v = r[j];
            const float* qq = q + 4 * j;
            acc += v.x * qq[0] + v.y * qq[1] + v.z * qq[2] + v.w * qq[3];
        }
        return acc;
    }
};

// ---- word-table accessors for the fallback path: WM 0=fp32, 1=bf16 --------
template <int WM> struct WT;
template <> struct WT<0> {
    static __device__ __forceinline__ void sixteen(const void* p, long i, float* o) {
        const float* s = (const float*)p + i;
        #pragma unroll
        for (int j = 0; j < 4; ++j) {
            float4 v = *(const float4*)(s + 4 * j);
            o[4*j] = v.x; o[4*j+1] = v.y; o[4*j+2] = v.z; o[4*j+3] = v.w;
        }
    }
    static __device__ __forceinline__ void four(const void* p, long i, float* o) {
        float4 v = *(const float4*)((const float*)p + i);
        o[0] = v.x; o[1] = v.y; o[2] = v.z; o[3] = v.w;
    }
};
template <> struct WT<1> {
    static __device__ __forceinline__ void sixteen(const void* p, long i, float* o) {
        const u16* s = (const u16*)p + i;
        #pragma unroll
        for (int j = 0; j < 2; ++j) {
            uint4 v = *(const uint4*)(s + 8 * j);
            float* q = o + 8 * j;
            q[0] = bf2f(v.x & 0xffffu); q[1] = bf2f(v.x >> 16);
            q[2] = bf2f(v.y & 0xffffu); q[3] = bf2f(v.y >> 16);
            q[4] = bf2f(v.z & 0xffffu); q[5] = bf2f(v.z >> 16);
            q[6] = bf2f(v.w & 0xffffu); q[7] = bf2f(v.w >> 16);
        }
    }
    static __device__ __forceinline__ void four(const void* p, long i, float* o) {
        uint2 v = *(const uint2*)((const u16*)p + i);
        o[0] = bf2f(v.x & 0xffffu); o[1] = bf2f(v.x >> 16);
        o[2] = bf2f(v.y & 0xffffu); o[3] = bf2f(v.y >> 16);
    }
};

// ---- in-kernel dtype sniff (fallback path only) ---------------------------
__device__ __forceinline__ int sniff_wave(const u16* p, int lane) {
    int bad = 0;
    #pragma unroll
    for (int j = 0; j < 8; ++j) {
        unsigned e = (p[lane * 8 + j] >> 7) & 0xffu;
        bad += (e >= 127u);
    }
    #pragma unroll
    for (int off = 1; off < 64; off <<= 1) bad += __shfl_xor(bad, off, 64);
    return (bad <= 16) ? 1 : 0;   // 1 = bf16, 0 = fp32
}

// ---- word table -> e5m2 in workspace; publishes dtype flag ---------------
__global__ void convert_words(const void* __restrict__ src, u32* __restrict__ dst,
                              u32* __restrict__ flagp) {
    __shared__ int s_flag;
    if (threadIdx.x < 64) {
        int f = sniff_wave((const u16*)src, (int)threadIdx.x);
        if (threadIdx.x == 0) s_flag = f;
    }
    __syncthreads();
    if (blockIdx.x == 0 && threadIdx.x == 0) flagp[0] = (u32)s_flag;
    long idx = (long)blockIdx.x * 256 + threadIdx.x;
    long i = idx * 16;
    if (i >= WELEMS) return;
    float v[16];
    if (s_flag == 0) {                        // fp32 source
        const float* s = (const float*)src + i;
        #pragma unroll
        for (int j = 0; j < 4; ++j) {
            float4 q = *(const float4*)(s + 4 * j);
            v[4*j] = q.x; v[4*j+1] = q.y; v[4*j+2] = q.z; v[4*j+3] = q.w;
        }
    } else {                                  // bf16 source
        WT<1>::sixteen(src, i, v);
    }
    uint4 o;
    o.x = e5m2_enc4(v); o.y = e5m2_enc4(v + 4);
    o.z = e5m2_enc4(v + 8); o.w = e5m2_enc4(v + 12);
    *(uint4*)(dst + idx * 4) = o;
}

// ---- shared-memory layout (single allocation for both dtype bodies) -------
struct SM {
    uint4 tile[NWAVES * TT * 8];   // 32 KiB raw e5m2 tiles (16B-aligned, first)
    float ww[NWAVES][TT];          // per-wave unnormalized weights
    float mem[DD];
    float memp[4][DD];             // mem-update partials (all-wave phase)
    float item[LL];
    float sent[SS * DD];
    int   uti[SS * TT];
    float sw[SS];
    float swf[SS];
    float swp[SS * 32];
    float q[LL];
    float ept[LL];
    float uemb[LL];
    int   fidx[CLIPN];
    float g[CLIPN];
    float a1[32];
    float a2[16];
    float alpha[2];
    float fnum;
    int   flag;
};

// ===========================================================================
// Fast body (reverted to the verified 270.9µs structure): e5m2 table,
// perm-decode -> half2, fdot2 score, LDS tile reuse for the weighted pass,
// deferred normalization, batched sw-reduce.
// R7 delta: mem-update phase parallelized across all 8 waves (was 2).
// ===========================================================================
template <bool BF16>
__device__ __forceinline__ void nrs_body(SM& sm,
              const int* __restrict__ user_idx,
              const int* __restrict__ item_idx,
              const void* __restrict__ wtab,
              const void* __restrict__ emb_item,
              const void* __restrict__ emb_user,
              const void* __restrict__ W_mem, const void* __restrict__ b_mem,
              const void* __restrict__ w_word, const void* __restrict__ b_word,
              const void* __restrict__ w_sent, const void* __restrict__ b_sent,
              const void* __restrict__ W_tr, const void* __restrict__ b_tr,
              const void* __restrict__ W1, const void* __restrict__ b1,
              const void* __restrict__ W2, const void* __restrict__ b2,
              const void* __restrict__ W3, const void* __restrict__ b3,
              const void* __restrict__ w_aff, const void* __restrict__ b_aff,
              const int* __restrict__ uti, const int* __restrict__ ufi,
              void* __restrict__ out)
{
    const int b = blockIdx.x;
    const int tid = (int)threadIdx.x;
    const int lane = tid & 63;
    const int wave = tid >> 6;

    const int u = user_idx[b];
    const int it = item_idx[b];
    const long utb = (long)u * (SS * TT);

    if (tid < LL) sm.item[tid] = LD<BF16>::one(emb_item, (long)it * LL + tid);
    __syncthreads();

    // mem = item_emb @ W_mem + b_mem (tid<128) | stage tweet indices (all)
    for (int i = tid; i < SS * TT; i += NTHREADS) sm.uti[i] = uti[utb + i];
    if (tid < DD) {
        float acc = LD<BF16>::one(b_mem, tid);
        #pragma unroll 8
        for (int l = 0; l < LL; ++l)
            acc += sm.item[l] * LD<BF16>::one(W_mem, l * DD + tid);
        sm.mem[tid] = acc;
    }
    __syncthreads();

    const float bw = LD<BF16>::one(b_word, 0);
    const float bs = LD<BF16>::one(b_sent, 0);
    const int t = lane >> 1, h = lane & 1;   // score-pass mapping: lane = 2t+h
    const int dq = lane & 31, th = lane >> 5;// weighted-pass mapping
    const int ctop = dq >> 2, cw = dq & 3;   // chunk / word-in-chunk for tile reads
    float ww4[4];
    #pragma unroll
    for (int k = 0; k < 4; ++k) ww4[k] = LD<BF16>::one(w_word, 4 * dq + k);
    const float ws0 = LD<BF16>::one(w_sent, lane);
    const float ws1 = LD<BF16>::one(w_sent, lane + 64);

    uint4* const twave = sm.tile + wave * (TT * 8);
    const u32* const trp = (const u32*)twave;
    h2 memh[32];

    for (int hoop = 0; hoop < 2; ++hoop) {
        // mem (f32, LDS) -> half2 pairs in registers for this lane's half
        {
            const float* mrow = &sm.mem[h * 64];
            #pragma unroll
            for (int k = 0; k < 32; ++k)
                memh[k] = pkrtz(mrow[2 * k], mrow[2 * k + 1]);
        }

        // prefetch first sentence's gather rows into registers
        uint4 w[4];
        {
            const int row0 = sm.uti[wave * TT + t];
            const uint4* gp0 = (const uint4*)((const char*)wtab +
                                              ((row0 << 7) + (h << 6)));
            #pragma unroll
            for (int j = 0; j < 4; ++j) w[j] = gp0[j];
        }

        for (int s = wave; s < SS; s += NWAVES) {
            // ---- issue next sentence's gathers (consumed next iteration) ----
            uint4 wn[4];
            {
                const int sn = (s + NWAVES < SS) ? (s + NWAVES) : s;
                const int rown = sm.uti[sn * TT + t];
                const uint4* gpn = (const uint4*)((const char*)wtab +
                                                  ((rown << 7) + (h << 6)));
                #pragma unroll
                for (int j = 0; j < 4; ++j) wn[j] = gpn[j];
            }

            // stash raw e5m2 tile (chunk-XOR swizzle: b128 writes at BW floor)
            {
                const int swz = t & 7;
                uint4* tp = twave + t * 8;
                #pragma unroll
                for (int j = 0; j < 4; ++j) tp[(h * 4 + j) ^ swz] = w[j];
            }

            // ---- score: lane = 2t+h owns 64 dims of row t; 4 parallel chains
            float a0 = 0.f, a1 = 0.f, a2 = 0.f, a3 = 0.f;
            #pragma unroll
            for (int j = 0; j < 4; ++j) {
                float* ap = (j == 0) ? &a0 : (j == 1) ? &a1 : (j == 2) ? &a2 : &a3;
                float ac = *ap;
                ac = FD2(declo(w[j].x), memh[8*j + 0], ac);
                ac = FD2(dechi(w[j].x), memh[8*j + 1], ac);
                ac = FD2(declo(w[j].y), memh[8*j + 2], ac);
                ac = FD2(dechi(w[j].y), memh[8*j + 3], ac);
                ac = FD2(declo(w[j].z), memh[8*j + 4], ac);
                ac = FD2(dechi(w[j].z), memh[8*j + 5], ac);
                ac = FD2(declo(w[j].w), memh[8*j + 6], ac);
                ac = FD2(dechi(w[j].w), memh[8*j + 7], ac);
                *ap = ac;
            }
            float acc = (a0 + a1) + (a2 + a3);
            acc += __shfl_xor(acc, 1, 64);   // score[t] in lanes 2t, 2t+1

            // unnormalized weight (|score| << 1 -> exp safe); publish to wave
            const float e = __expf(acc);
            if (h == 0) sm.ww[wave][t] = e;

            // broadcast-read this half's 16 unnormalized weights, pack to h2
            h2 wh2[16];
            {
                const float* wp = &sm.ww[wave][th * 16];
                #pragma unroll
                for (int jj = 0; jj < 4; ++jj) {
                    float4 qv = *(const float4*)(wp + 4 * jj);
                    wh2[4*jj+0] = pkrtz(qv.x, qv.x);
                    wh2[4*jj+1] = pkrtz(qv.y, qv.y);
                    wh2[4*jj+2] = pkrtz(qv.z, qv.z);
                    wh2[4*jj+3] = pkrtz(qv.w, qv.w);
                }
            }

            // ---- weighted pass (e-weighted): lane (th,dq) dims [4dq,4dq+4) ----
            __threadfence_block();           // tile writes -> visible to reads
            h2 p0a = u2h(0u), p0b = u2h(0u), p1a = u2h(0u), p1b = u2h(0u);
            #pragma unroll
            for (int i2 = 0; i2 < 16; ++i2) {
                const int t2 = th * 16 + i2;
                const u32 wrd = trp[t2 * 32 + ((ctop ^ (i2 & 7)) << 2) + cw];
                const h2 wh = wh2[i2];
                if (i2 & 1) { p0b += declo(wrd) * wh; p1b += dechi(wrd) * wh; }
                else        { p0a += declo(wrd) * wh; p1a += dechi(wrd) * wh; }
            }
            h2 pa0 = p0a + p0b, pa1 = p1a + p1b;
            pa0 += u2h((u32)__shfl_xor((int)h2u(pa0), 32, 64));
            pa1 += u2h((u32)__shfl_xor((int)h2u(pa1), 32, 64));

            // softmax denominator (no consumer until here -> overlaps above)
            float smd = e;
            #pragma unroll
            for (int off = 2; off < 64; off <<= 1) smd += __shfl_xor(smd, off, 64);
            const float inv = 1.f / smd;

            const float f0 = (float)pa0.x * inv, f1 = (float)pa0.y * inv;
            const float f2 = (float)pa1.x * inv, f3 = (float)pa1.y * inv;
            if (th == 0) {
                *(float4*)&sm.sent[s * DD + 4 * dq] = make_float4(f0, f1, f2, f3);
                // sw partial (4 dims); reduced in the batched phase below
                sm.swp[s * 32 + dq] =
                    f0 * ww4[0] + f1 * ww4[1] + f2 * ww4[2] + f3 * ww4[3];
            }

            // rotate prefetch buffer
            #pragma unroll
            for (int j = 0; j < 4; ++j) w[j] = wn[j];
        }
        __syncthreads();

        // batched sw reduction: each wave reduces its own sentences (ILP-rich)
        for (int s2 = wave; s2 < SS; s2 += NWAVES) {
            float v = sm.swp[s2 * 32 + (lane & 31)];
            #pragma unroll
            for (int off = 1; off < 32; off <<= 1) v += __shfl_xor(v, off, 64);
            if (lane == 0) sm.sw[s2] = v + bw;
        }
        __syncthreads();

        // sentence-level softmax (wave 0); tanh in [-1,1] -> no max needed
        if (wave == 0) {
            float p = sm.mem[lane] * ws0 + sm.mem[lane + 64] * ws1;
            #pragma unroll
            for (int off = 1; off < 64; off <<= 1) p += __shfl_xor(p, off, 64);
            float iw = p + bs;
            float e2 = (lane < SS) ? __expf(tanhf(sm.sw[lane] + iw)) : 0.f;
            float smm = e2;
            #pragma unroll
            for (int off = 1; off < 64; off <<= 1) smm += __shfl_xor(smm, off, 64);
            if (lane < SS) sm.swf[lane] = e2 / smm;
        }
        __syncthreads();

        // mem update: all 8 waves participate (4-way split over sentences)
        {
            const int d2 = tid & (DD - 1);
            const int qq = tid >> 7;          // 0..3
            float acc = 0.f;
            for (int s2 = qq; s2 < SS; s2 += 4)
                acc += sm.swf[s2] * sm.sent[s2 * DD + d2];
            sm.memp[qq][d2] = acc;
        }
        __syncthreads();
        if (tid < DD)
            sm.mem[tid] += sm.memp[0][tid] + sm.memp[1][tid]
                         + sm.memp[2][tid] + sm.memp[3][tid];
        __syncthreads();
    }

    // ---------------- tail ----------------
    if (tid < LL) {
        float acc = LD<BF16>::one(b_tr, tid);
        for (int d = 0; d < DD; ++d)
            acc += sm.mem[d] * LD<BF16>::one(W_tr, d * LL + tid);
        sm.ept[tid] = acc;
    } else if (tid < 128) {
        int l = tid - 64;
        sm.q[l] = sm.item[l] * LD<BF16>::one(w_aff, l);
    } else if (tid < 128 + CLIPN) {
        sm.fidx[tid - 128] = ufi[(long)u * CLIPN + (tid - 128)];
    } else if (tid >= 192 && tid < 224) {
        int j = tid - 192;
        float acc = LD<BF16>::one(b1, j);
        for (int l = 0; l < LL; ++l)
            acc += sm.item[l] * LD<BF16>::one(W1, l * 32 + j);
        sm.a1[j] = sigf(acc);
    }
    __syncthreads();

    const float baff = LD<BF16>::one(b_aff, 0);
    if (tid < CLIPN) {
        long fb = (long)sm.fidx[tid] * LL;
        float g = sigf(LD<BF16>::dot64(emb_user, fb, sm.q) + baff);
        sm.g[tid] = g;
        LD<BF16>::st(out, NB + (long)b * CLIPN + tid, g);
    } else if (tid >= 64 && tid < 80) {
        int j = tid - 64;
        float acc = LD<BF16>::one(b2, j);
        for (int k = 0; k < 32; ++k) acc += sm.a1[k] * LD<BF16>::one(W2, k * 16 + j);
        sm.a2[j] = sigf(acc);
    } else if (tid == 80) {
        int cnt = 0;
        for (int c = 0; c < CLIPN; ++c) cnt += (sm.fidx[c] == NFRIENDS);
        sm.fnum = (float)(CLIPN - cnt);
    }
    __syncthreads();

    if (tid >= 64 && tid < 128) {
        int l = tid - 64;
        float acc = 0.f;
        for (int c = 0; c < CLIPN; ++c)
            acc += sm.g[c] * LD<BF16>::one(emb_user, (long)sm.fidx[c] * LL + l);
        sm.uemb[l] = acc;
    } else if (tid < 2) {
        float acc = LD<BF16>::one(b3, tid);
        for (int k = 0; k < 16; ++k) acc += sm.a2[k] * LD<BF16>::one(W3, k * 2 + tid);
        sm.alpha[tid] = sigf(acc);
    }
    __syncthreads();

    if (wave == 0) {
        float vec = sm.alpha[0] * sm.ept[lane] + sm.alpha[1] * (sm.uemb[lane] / sm.fnum);
        float p = vec * sm.q[lane];
        #pragma unroll
        for (int off = 1; off < 64; off <<= 1) p += __shfl_xor(p, off, 64);
        if (lane == 0) LD<BF16>::st(out, b, sigf(p + baff));
    }
}

// single kernel: uniform branch on dtype flag; one shared allocation
__global__ __launch_bounds__(NTHREADS, 4)
void nrs_fast(const int* __restrict__ user_idx,
              const int* __restrict__ item_idx,
              const void* __restrict__ wtab,
              const void* __restrict__ emb_item,
              const void* __restrict__ emb_user,
              const void* __restrict__ W_mem, const void* __restrict__ b_mem,
              const void* __restrict__ w_word, const void* __restrict__ b_word,
              const void* __restrict__ w_sent, const void* __restrict__ b_sent,
              const void* __restrict__ W_tr, const void* __restrict__ b_tr,
              const void* __restrict__ W1, const void* __restrict__ b1,
              const void* __restrict__ W2, const void* __restrict__ b2,
              const void* __restrict__ W3, const void* __restrict__ b3,
              const void* __restrict__ w_aff, const void* __restrict__ b_aff,
              const int* __restrict__ uti, const int* __restrict__ ufi,
              void* __restrict__ out,
              const u32* __restrict__ flagp)
{
    __shared__ SM sm;
    if (threadIdx.x == 0) sm.flag = (int)flagp[0];
    __syncthreads();
    if (sm.flag == 1)
        nrs_body<true>(sm, user_idx, item_idx, wtab, emb_item, emb_user,
                       W_mem, b_mem, w_word, b_word, w_sent, b_sent, W_tr, b_tr,
                       W1, b1, W2, b2, W3, b3, w_aff, b_aff, uti, ufi, out);
    else
        nrs_body<false>(sm, user_idx, item_idx, wtab, emb_item, emb_user,
                        W_mem, b_mem, w_word, b_word, w_sent, b_sent, W_tr, b_tr,
                        W1, b1, W2, b2, W3, b3, w_aff, b_aff, uti, ufi, out);
}

// ===========================================================================
// Fallback generic kernel (no workspace): original structure, WM 0/1 only.
// ===========================================================================
template <bool BF16, int WM>
__global__ __launch_bounds__(NTHREADS, 4)
void nrs_generic(const int* __restrict__ user_idx,
                 const int* __restrict__ item_idx,
                 const void* __restrict__ wtab,
                 const void* __restrict__ emb_item,
                 const void* __restrict__ emb_user,
                 const void* __restrict__ W_mem, const void* __restrict__ b_mem,
                 const void* __restrict__ w_word, const void* __restrict__ b_word,
                 const void* __restrict__ w_sent, const void* __restrict__ b_sent,
                 const void* __restrict__ W_tr, const void* __restrict__ b_tr,
                 const void* __restrict__ W1, const void* __restrict__ b1,
                 const void* __restrict__ W2, const void* __restrict__ b2,
                 const void* __restrict__ W3, const void* __restrict__ b3,
                 const void* __restrict__ w_aff, const void* __restrict__ b_aff,
                 const int* __restrict__ uti, const int* __restrict__ ufi,
                 void* __restrict__ out)
{
    __shared__ float s_mem[DD];
    __shared__ float s_item[LL];
    __shared__ float s_sent[SS * DD];
    __shared__ int   s_uti[SS * TT];
    __shared__ float s_sw[SS];
    __shared__ float s_swf[SS];
    __shared__ float s_q[LL];
    __shared__ float s_ept[LL];
    __shared__ float s_uemb[LL];
    __shared__ int   s_fidx[CLIPN];
    __shared__ float s_g[CLIPN];
    __shared__ float s_a1[32];
    __shared__ float s_a2[16];
    __shared__ float s_alpha[2];
    __shared__ float s_fnum;
    __shared__ int   s_flag;

    const int b = blockIdx.x;
    const int tid = (int)threadIdx.x;
    const int lane = tid & 63;
    const int wave = tid >> 6;

    if (tid < 64) {
        int f = sniff_wave((const u16*)wtab, lane);
        if (tid == 0) s_flag = f;
    }
    __syncthreads();
    if (s_flag != (BF16 ? 1 : 0)) return;

    const int u = user_idx[b];
    const int it = item_idx[b];
    const long utb = (long)u * (SS * TT);

    if (tid < LL) s_item[tid] = LD<BF16>::one(emb_item, (long)it * LL + tid);
    __syncthreads();

    for (int i = tid; i < SS * TT; i += NTHREADS) s_uti[i] = uti[utb + i];
    if (tid < DD) {
        float acc = LD<BF16>::one(b_mem, tid);
        #pragma unroll 8
        for (int l = 0; l < LL; ++l)
            acc += s_item[l] * LD<BF16>::one(W_mem, l * DD + tid);
        s_mem[tid] = acc;
    }
    __syncthreads();

    const float bw = LD<BF16>::one(b_word, 0);
    const float bs = LD<BF16>::one(b_sent, 0);
    const int dq = lane & 31;
    const int th = lane >> 5;
    float ww4[4];
    #pragma unroll
    for (int k = 0; k < 4; ++k) ww4[k] = LD<BF16>::one(w_word, 4 * dq + k);
    const float ws0 = LD<BF16>::one(w_sent, lane);
    const float ws1 = LD<BF16>::one(w_sent, lane + 64);

    for (int hoop = 0; hoop < 2; ++hoop) {
        for (int s = wave; s < SS; s += NWAVES) {
            const int t = lane >> 1, h = lane & 1;
            const int row = s_uti[s * TT + t];
            const long base = (long)row * DD + h * 64;
            float acc = 0.f;
            #pragma unroll
            for (int j = 0; j < 4; ++j) {
                float v16[16];
                WT<WM>::sixteen(wtab, base + 16 * j, v16);
                const float* mp = &s_mem[h * 64 + 16 * j];
                #pragma unroll
                for (int k = 0; k < 16; ++k) acc += v16[k] * mp[k];
            }
            acc += __shfl_xor(acc, 1, 64);

            float mx = acc;
            #pragma unroll
            for (int off = 1; off < 64; off <<= 1) mx = fmaxf(mx, __shfl_xor(mx, off, 64));
            float e = expf(acc - mx);
            float sm = e;
            #pragma unroll
            for (int off = 1; off < 64; off <<= 1) sm += __shfl_xor(sm, off, 64);
            float wwt = 2.f * e / sm;

            float a4[4] = {0.f, 0.f, 0.f, 0.f};
            #pragma unroll 4
            for (int i2 = 0; i2 < 16; ++i2) {
                int t2 = th * 16 + i2;
                float wv = __shfl(wwt, 2 * t2, 64);
                int r2 = s_uti[s * TT + t2];
                float v4[4];
                WT<WM>::four(wtab, (long)r2 * DD + 4 * dq, v4);
                #pragma unroll
                for (int k = 0; k < 4; ++k) a4[k] += wv * v4[k];
            }
            #pragma unroll
            for (int k = 0; k < 4; ++k) a4[k] += __shfl_xor(a4[k], 32, 64);
            if (th == 0)
                *(float4*)&s_sent[s * DD + 4 * dq] =
                    make_float4(a4[0], a4[1], a4[2], a4[3]);

            float p = a4[0] * ww4[0] + a4[1] * ww4[1] + a4[2] * ww4[2] + a4[3] * ww4[3];
            #pragma unroll
            for (int off = 1; off < 64; off <<= 1) p += __shfl_xor(p, off, 64);
            if (lane == 0) s_sw[s] = 0.5f * p + bw;
        }
        __syncthreads();

        if (wave == 0) {
            float p = s_mem[lane] * ws0 + s_mem[lane + 64] * ws1;
            #pragma unroll
            for (int off = 1; off < 64; off <<= 1) p += __shfl_xor(p, off, 64);
            float iw = p + bs;
            float v = (lane < SS) ? tanhf(s_sw[lane] + iw) : -2.f;
            float mx = v;
            #pragma unroll
            for (int off = 1; off < 64; off <<= 1) mx = fmaxf(mx, __shfl_xor(mx, off, 64));
            float e = (lane < SS) ? expf(v - mx) : 0.f;
            float sm = e;
            #pragma unroll
            for (int off = 1; off < 64; off <<= 1) sm += __shfl_xor(sm, off, 64);
            if (lane < SS) s_swf[lane] = e / sm;
        }
        __syncthreads();

        if (tid < DD) {
            float acc = s_mem[tid];
            for (int s2 = 0; s2 < SS; ++s2)
                acc += s_swf[s2] * s_sent[s2 * DD + tid];
            s_mem[tid] = acc;
        }
        __syncthreads();
    }

    if (tid < LL) {
        float acc = LD<BF16>::one(b_tr, tid);
        for (int d = 0; d < DD; ++d)
            acc += s_mem[d] * LD<BF16>::one(W_tr, d * LL + tid);
        s_ept[tid] = acc;
    } else if (tid < 128) {
        int l = tid - 64;
        s_q[l] = s_item[l] * LD<BF16>::one(w_aff, l);
    } else if (tid < 128 + CLIPN) {
        s_fidx[tid - 128] = ufi[(long)u * CLIPN + (tid - 128)];
    } else if (tid >= 192 && tid < 224) {
        int j = tid - 192;
        float acc = LD<BF16>::one(b1, j);
        for (int l = 0; l < LL; ++l)
            acc += s_item[l] * LD<BF16>::one(W1, l * 32 + j);
        s_a1[j] = sigf(acc);
    }
    __syncthreads();

    const float baff = LD<BF16>::one(b_aff, 0);
    if (tid < CLIPN) {
        long fb = (long)s_fidx[tid] * LL;
        float acc = 0.f;
        for (int l = 0; l < LL; ++l) acc += LD<BF16>::one(emb_user, fb + l) * s_q[l];
        float g = sigf(acc + baff);
        s_g[tid] = g;
        LD<BF16>::st(out, NB + (long)b * CLIPN + tid, g);
    } else if (tid >= 64 && tid < 80) {
        int j = tid - 64;
        float acc = LD<BF16>::one(b2, j);
        for (int k = 0; k < 32; ++k) acc += s_a1[k] * LD<BF16>::one(W2, k * 16 + j);
        s_a2[j] = sigf(acc);
    } else if (tid == 80) {
        int cnt = 0;
        for (int c = 0; c < CLIPN; ++c) cnt += (s_fidx[c] == NFRIENDS);
        s_fnum = (float)(CLIPN - cnt);
    }
    __syncthreads();

    if (tid >= 64 && tid < 128) {
        int l = tid - 64;
        float acc = 0.f;
        for (int c = 0; c < CLIPN; ++c)
            acc += s_g[c] * LD<BF16>::one(emb_user, (long)s_fidx[c] * LL + l);
        s_uemb[l] = acc;
    } else if (tid < 2) {
        float acc = LD<BF16>::one(b3, tid);
        for (int k = 0; k < 16; ++k) acc += s_a2[k] * LD<BF16>::one(W3, k * 2 + tid);
        s_alpha[tid] = sigf(acc);
    }
    __syncthreads();

    if (wave == 0) {
        float vec = s_alpha[0] * s_ept[lane] + s_alpha[1] * (s_uemb[lane] / s_fnum);
        float p = vec * s_q[lane];
        #pragma unroll
        for (int off = 1; off < 64; off <<= 1) p += __shfl_xor(p, off, 64);
        if (lane == 0) LD<BF16>::st(out, b, sigf(p + baff));
    }
}

extern "C" void kernel_launch(void* const* d_in, const int* in_sizes, int n_in,
                              void* d_out, int out_size, void* d_ws, size_t ws_size,
                              hipStream_t stream) {
    (void)in_sizes; (void)n_in; (void)out_size;
    u32* wbuf = (u32*)d_ws;
    u32* flagp = wbuf + (WELEMS / 4);               // flag just past the table
    const bool ws_ok = ws_size >= (size_t)WELEMS + 64;

    if (ws_ok) {
        const long nthr = (WELEMS + 15) / 16;
        convert_words<<<(int)((nthr + 255) / 256), 256, 0, stream>>>(
            d_in[2], wbuf, flagp);
        nrs_fast<<<NB, NTHREADS, 0, stream>>>(
            (const int*)d_in[0], (const int*)d_in[1], (const void*)wbuf,
            d_in[3], d_in[4], d_in[5], d_in[6], d_in[7], d_in[8], d_in[9],
            d_in[10], d_in[11], d_in[12], d_in[13], d_in[14], d_in[15],
            d_in[16], d_in[17], d_in[18], d_in[19], d_in[20],
            (const int*)d_in[21], (const int*)d_in[22], d_out, flagp);
    } else {
        nrs_generic<true, 1><<<NB, NTHREADS, 0, stream>>>(
            (const int*)d_in[0], (const int*)d_in[1], d_in[2],
            d_in[3], d_in[4], d_in[5], d_in[6], d_in[7], d_in[8], d_in[9],
            d_in[10], d_in[11], d_in[12], d_in[13], d_in[14], d_in[15],
            d_in[16], d_in[17], d_in[18], d_in[19], d_in[20],
            (const int*)d_in[21], (const int*)d_in[22], d_out);
        nrs_generic<false, 0><<<NB, NTHREADS, 0, stream>>>(
            (const int*)d_in[0], (const int*)d_in[1], d_in[2],
            d_in[3], d_in[4], d_in[5], d_in[6], d_in[7], d_in[8], d_in[9],
            d_in[10], d_in[11], d_in[12], d_in[13], d_in[14], d_in[15],
            d_in[16], d_in[17], d_in[18], d_in[19], d_in[20],
            (const int*)d_in[21], (const int*)d_in[22], d_out);
    }
}